// Round 11
// baseline (248.655 us; speedup 1.0000x reference)
//
#include <hip/hip_runtime.h>
#include <math.h>

#define B 4
#define C 64
#define H 256
#define W 256
#define CMID 16
#define CIN 73        // 64 + 9
#define HW (H*W)
#define NW (CIN*9*CMID)   // 10512 conv1 weights
#define XS_STRIDE 260     // offset kernel LDS row stride
#define PLN 258           // conv1 transposed row stride: 256 data + 2 halo slots
#define SE  258           // sim parity-split row stride

// ---------------------------------------------------------------------------
// Local cosine similarity. FROZEN (r10): r8 structure + folded w1 transpose.
// ---------------------------------------------------------------------------
__global__ __launch_bounds__(256) void sim_kernel(const float* __restrict__ x,
                                                  float* __restrict__ sim,
                                                  const float* __restrict__ w1,
                                                  float* __restrict__ wt) {
    __shared__ float xs[2][4][4 * SE];   // 33024 B

    int bid = blockIdx.x;
    int tid = threadIdx.x;

    {   // folded transpose: wt[(ci*9+k)*CMID+co] = w1[(co*CIN+ci)*9+k]
        int gidx = bid * 256 + tid;
        if (gidx < NW) {
            int co = gidx & (CMID - 1);
            int rest = gidx >> 4;
            int ci = rest / 9;
            int k = rest - ci * 9;
            wt[gidx] = w1[(co * CIN + ci) * 9 + k];
        }
    }

    int sb = (bid & 7) * 64 + (bid >> 3);    // XCD-contiguous bands (512 = 8*64)
    int b  = sb >> 7;
    int y0 = (sb & 127) << 1;
    int rl = tid >> 7;             // output row 0/1
    int k  = tid & 127;            // pixel-pair index
    int px = k << 1;
    int y  = y0 + rl;

    int scol = (tid & 1) ? 130 + (tid >> 1) : (tid >> 1);   // parity-split dst

    bool rv[4];
    size_t off[4];
#pragma unroll
    for (int j = 0; j < 4; ++j) {
        int grow = y0 - 1 + j;
        rv[j] = (grow >= 0) && (grow < H);
        off[j] = (size_t)grow * W + tid;
    }

    if (tid < 64) {   // zero slots 128/129: 2 bufs x 4 ch x 4 rows x 2
        int e = tid & 1;
        int r = (tid >> 1) & 3;
        int q = tid >> 3;          // buf*4 + ch
        (&xs[0][0][0])[q * (4 * SE) + r * SE + 128 + e] = 0.f;
    }

    float dot0[9], nsq0[9], dot1[9], nsq1[9];
    float csq0 = 0.f, csq1 = 0.f;
#pragma unroll
    for (int i = 0; i < 9; ++i) { dot0[i] = dot1[i] = nsq0[i] = nsq1[i] = 0.f; }

    const float* xb = x + (size_t)b * C * HW;
    float p[16];
#pragma unroll
    for (int kk = 0; kk < 4; ++kk)
#pragma unroll
        for (int j = 0; j < 4; ++j)
            p[kk * 4 + j] = rv[j] ? xb[(size_t)kk * HW + off[j]] : 0.f;

    int cur = 0;
#pragma unroll 1
    for (int cc = 0; cc < C; cc += 4) {
#pragma unroll
        for (int kk = 0; kk < 4; ++kk)
#pragma unroll
            for (int j = 0; j < 4; ++j)
                xs[cur][kk][j * SE + scol] = p[kk * 4 + j];
        __syncthreads();

        if (cc + 4 < C) {
#pragma unroll
            for (int kk = 0; kk < 4; ++kk)
#pragma unroll
                for (int j = 0; j < 4; ++j)
                    p[kk * 4 + j] = rv[j] ? xb[(size_t)(cc + 4 + kk) * HW + off[j]] : 0.f;
        }

#pragma unroll
        for (int kk = 0; kk < 4; ++kk) {
            const float* base = &xs[cur][kk][rl * SE];
            float v[3][4];
#pragma unroll
            for (int r = 0; r < 3; ++r) {
                const float* rp = base + r * SE;
                v[r][0] = rp[129 + k];   // col px-1
                v[r][1] = rp[k];         // col px
                v[r][2] = rp[130 + k];   // col px+1
                v[r][3] = rp[k + 1];     // col px+2
            }
            float cv0 = v[1][1], cv1 = v[1][2];
            csq0 = fmaf(cv0, cv0, csq0);
            csq1 = fmaf(cv1, cv1, csq1);
#pragma unroll
            for (int kr = 0; kr < 3; ++kr)
#pragma unroll
                for (int kc = 0; kc < 3; ++kc) {
                    int kk9 = kr * 3 + kc;
                    if (kk9 == 4) continue;
                    float n0 = v[kr][kc], n1 = v[kr][kc + 1];
                    dot0[kk9] = fmaf(cv0, n0, dot0[kk9]);
                    nsq0[kk9] = fmaf(n0, n0, nsq0[kk9]);
                    dot1[kk9] = fmaf(cv1, n1, dot1[kk9]);
                    nsq1[kk9] = fmaf(n1, n1, nsq1[kk9]);
                }
        }
        cur ^= 1;
    }

    dot0[4] = csq0; nsq0[4] = csq0;
    dot1[4] = csq1; nsq1[4] = csq1;
    float cn0 = sqrtf(csq0) + 1e-8f;
    float cn1 = sqrtf(csq1) + 1e-8f;
    float* so = sim + (size_t)b * 9 * HW + (size_t)y * W + px;
#pragma unroll
    for (int kk9 = 0; kk9 < 9; ++kk9) {
        float s0 = dot0[kk9] / (cn0 * (sqrtf(nsq0[kk9]) + 1e-8f));
        float s1 = dot1[kk9] / (cn1 * (sqrtf(nsq1[kk9]) + 1e-8f));
        *(float2*)(so + (size_t)kk9 * HW) = make_float2(s0, s1);
    }
}

// ---------------------------------------------------------------------------
// Conv1 (73->16), K-SPLIT occupancy test: grid 1024 = 512 (b,y0) x 2 halves.
// Half 0: ch 0..35 (+bias); half 1: ch 36..72. Each block = exact r5
// structure (co-split waves, transposed conflict-free LDS, forced-VMEM dbuf
// weights) — per-wave per-channel instruction mix UNCHANGED, so this tests
// pure concurrency: 4 blocks/CU -> 4 waves/SIMD (2x r5). Partials written
// RAW (no leaky — nonlinear; applied in offset after summing hp0+hp1).
// ---------------------------------------------------------------------------
__device__ __forceinline__ void conv1_co4(const float* __restrict__ pl, int l,
                                          int aL, int aR,
                                          const float4 wv[9], float4 acc[2][4]) {
    float v[4][6];
#pragma unroll
    for (int r = 0; r < 4; ++r) {
        const float* rp = pl + r * PLN;
        v[r][1] = rp[l];
        v[r][2] = rp[64 + l];
        v[r][3] = rp[128 + l];
        v[r][4] = rp[192 + l];
        v[r][0] = rp[aL];     // col 4l-1  (lane 0 -> slot 256 = 0)
        v[r][5] = rp[aR];     // col 4l+4  (lane 63 -> slot 257 = 0)
    }
#pragma unroll
    for (int kr = 0; kr < 3; ++kr)
#pragma unroll
        for (int kc = 0; kc < 3; ++kc) {
            float4 w = wv[kr * 3 + kc];
#pragma unroll
            for (int rr = 0; rr < 2; ++rr)
#pragma unroll
                for (int cc = 0; cc < 4; ++cc) {
                    float a = v[rr + kr][cc + kc];
                    acc[rr][cc].x = fmaf(a, w.x, acc[rr][cc].x);
                    acc[rr][cc].y = fmaf(a, w.y, acc[rr][cc].y);
                    acc[rr][cc].z = fmaf(a, w.z, acc[rr][cc].z);
                    acc[rr][cc].w = fmaf(a, w.w, acc[rr][cc].w);
                }
        }
}

__global__ __launch_bounds__(256) void conv1_kernel(const float* __restrict__ x,
                                                    const float* __restrict__ sim,
                                                    const float* __restrict__ wt,
                                                    const float* __restrict__ b1,
                                                    float* __restrict__ hp0,
                                                    float* __restrict__ hp1) {
    __shared__ float xs[2][2][4 * PLN];   // 16512 B -> 4 blocks/CU fits

    int tid = threadIdx.x;
    int l = tid & 63;
    int wid = tid >> 6;
    int bid = blockIdx.x;
    int half = bid & 1;
    int inner = bid >> 1;                     // 0..511
    int sb = (inner & 7) * 64 + (inner >> 3); // XCD-contiguous bands
    int b  = sb >> 7;
    int y0 = (sb & 127) << 1;

    int cstart = half ? 36 : 0;
    int climit = half ? 73 : 36;              // prefetch bound (h1 includes tail 72)

    // Opaque VGPR zero: keeps wave-uniform weight loads on the VMEM path
    // (vmcnt), not the scalar path (lgkmcnt drain poison — r0/r1 lesson).
    int vz;
    asm volatile("v_mov_b32 %0, 0" : "=v"(vz));
    const float4* wq = (const float4*)wt + vz;

    const float* gx = x + (size_t)b * C * HW;
    const float* gs = sim + (size_t)b * 9 * HW;

    int grow = y0 - 1 + wid;
    bool rvw = (grow >= 0) && (grow < H);
    size_t goff = (size_t)grow * W + 4 * l;

    int aL = (l == 0)  ? 256 : 191 + l;
    int aR = (l == 63) ? 257 : l + 1;

    if (tid < 32) {
        int bu = tid >> 4, ch = (tid >> 3) & 1, r = (tid >> 1) & 3, e = tid & 1;
        xs[bu][ch][r * PLN + 256 + e] = 0.f;
    }

    const float4 z4 = make_float4(0.f, 0.f, 0.f, 0.f);
    float4 acc[2][4];
    {
        float4 init = half ? z4 : ((const float4*)b1)[wid];
#pragma unroll
        for (int rr = 0; rr < 2; ++rr)
#pragma unroll
            for (int cc = 0; cc < 4; ++cc) acc[rr][cc] = init;
    }

    float4 wA[9], wB[9];
#pragma unroll
    for (int k = 0; k < 9; ++k) wA[k] = wq[(cstart * 9 + k) * 4 + wid];

    float4 p0 = z4, p1 = z4;
    if (rvw) {                                 // cstart, cstart+1 both < C
        p0 = *(const float4*)(gx + (size_t)cstart * HW + goff);
        p1 = *(const float4*)(gx + (size_t)(cstart + 1) * HW + goff);
    }

    int cur = 0;
#pragma unroll 1
    for (int cc2 = cstart; cc2 < cstart + 36; cc2 += 2) {
        {   // transposed staging: 4x b32 stride-1 per channel
            float* d0 = &xs[cur][0][wid * PLN];
            d0[l] = p0.x; d0[64 + l] = p0.y; d0[128 + l] = p0.z; d0[192 + l] = p0.w;
            float* d1 = &xs[cur][1][wid * PLN];
            d1[l] = p1.x; d1[64 + l] = p1.y; d1[128 + l] = p1.z; d1[192 + l] = p1.w;
        }
        __syncthreads();

        // prefetch activations cc2+2, cc2+3 (bounded by this half's climit)
        {
            int ci = cc2 + 2;
            p0 = z4;
            if (rvw && ci < climit)
                p0 = (ci < C) ? *(const float4*)(gx + (size_t)ci * HW + goff)
                              : *(const float4*)(gs + (size_t)(ci - C) * HW + goff);
            int cj = cc2 + 3;
            p1 = z4;
            if (rvw && cj < climit)
                p1 = (cj < C) ? *(const float4*)(gx + (size_t)cj * HW + goff)
                              : *(const float4*)(gs + (size_t)(cj - C) * HW + goff);
        }

#pragma unroll
        for (int k = 0; k < 9; ++k) wB[k] = wq[((cc2 + 1) * 9 + k) * 4 + wid];

        conv1_co4(&xs[cur][0][0], l, aL, aR, wA, acc);

#pragma unroll
        for (int k = 0; k < 9; ++k) wA[k] = wq[((cc2 + 2) * 9 + k) * 4 + wid];

        conv1_co4(&xs[cur][1][0], l, aL, aR, wB, acc);

        cur ^= 1;
    }

    // tail channel ci = 72 — half 1 only (p0/wA prefetched at cc2=70)
    if (half) {
        float* d0 = &xs[cur][0][wid * PLN];
        d0[l] = p0.x; d0[64 + l] = p0.y; d0[128 + l] = p0.z; d0[192 + l] = p0.w;
        __syncthreads();
        conv1_co4(&xs[cur][0][0], l, aL, aR, wA, acc);
    }

    // epilogue: RAW partial (no leaky), transpose acc, float4 stores
    float* hp = half ? hp1 : hp0;
    float* ho = hp + ((size_t)b * CMID + 4 * wid) * HW + (size_t)y0 * W + 4 * l;
#pragma unroll
    for (int rr = 0; rr < 2; ++rr)
#pragma unroll
        for (int j = 0; j < 4; ++j) {
            float4 o;
            o.x = ((const float*)&acc[rr][0])[j];
            o.y = ((const float*)&acc[rr][1])[j];
            o.z = ((const float*)&acc[rr][2])[j];
            o.w = ((const float*)&acc[rr][3])[j];
            *(float4*)(ho + (size_t)j * HW + (size_t)rr * W) = o;
        }
}

// ---------------------------------------------------------------------------
// Strip helpers for offset kernel (2-px/thread structure, stride 260).
// ---------------------------------------------------------------------------
__device__ __forceinline__ void read_patch_lds(const float* __restrict__ xsbuf,
                                               int rl, int px, float v[3][4]) {
    const float* pb = xsbuf + rl * XS_STRIDE + px;
#pragma unroll
    for (int r = 0; r < 3; ++r) {
        float2 p0 = *(const float2*)(pb + r * XS_STRIDE);
        float2 p1 = *(const float2*)(pb + r * XS_STRIDE + 2);
        v[r][0] = p0.x; v[r][1] = p0.y; v[r][2] = p1.x; v[r][3] = p1.y;
    }
}

// ---------------------------------------------------------------------------
// Conv2 (16->2) + tanh -> clamped sample coords. r9 structure (4 ch/barrier)
// CHANGED: h = leaky(hp0 + hp1) computed at staging (K-split companion).
// ---------------------------------------------------------------------------
__global__ __launch_bounds__(256) void offset_kernel(const float* __restrict__ hp0,
                                                     const float* __restrict__ hp1,
                                                     const float* __restrict__ w2,
                                                     const float* __restrict__ b2,
                                                     float2* __restrict__ off_buf) {
    __shared__ float lw2[CMID * 9 * 2];
    __shared__ float xs[2][4][4 * XS_STRIDE];   // 33280 B

    int tid = threadIdx.x;
    for (int i = tid; i < CMID * 9 * 2; i += 256) {
        int co = i & 1;
        int rest = i >> 1;
        int ci = rest / 9;
        int kk = rest - ci * 9;
        lw2[i] = w2[(co * CMID + ci) * 9 + kk];
    }

    int bid = blockIdx.x;
    int sb = (bid & 7) * 64 + (bid >> 3);    // XCD-contiguous bands (512 = 8*64)
    int b  = sb >> 7;
    int y0 = (sb & 127) << 1;
    int srow = tid >> 6;
    int sx4  = (tid & 63) << 2;
    int rl = tid >> 7;
    int px = (tid & 127) << 1;
    int y  = y0 + rl;

    int grow = y0 - 1 + srow;
    bool gvalid = (grow >= 0) && (grow < H);
    size_t hoff = (size_t)b * CMID * HW + (size_t)grow * W + sx4;
    const float* gh0 = hp0 + hoff;
    const float* gh1 = hp1 + hoff;

    if (tid < 64) {   // zero halo cols: 2 bufs x 4 ch x 4 rows x {0,257}
        int bu = tid >> 5, ch = (tid >> 3) & 3, r = (tid >> 1) & 3;
        int e = (tid & 1) ? 257 : 0;
        xs[bu][ch][r * XS_STRIDE + e] = 0.f;
    }

    float s0x = b2[0], s0y = b2[1], s1x = b2[0], s1y = b2[1];

    const float4 z4 = make_float4(0.f, 0.f, 0.f, 0.f);
    float4 pa[4], pb[4];
#pragma unroll
    for (int k = 0; k < 4; ++k) {
        pa[k] = gvalid ? *(const float4*)(gh0 + (size_t)k * HW) : z4;
        pb[k] = gvalid ? *(const float4*)(gh1 + (size_t)k * HW) : z4;
    }

    int cur = 0;
#pragma unroll 1
    for (int cg4 = 0; cg4 < CMID; cg4 += 4) {
#pragma unroll
        for (int k = 0; k < 4; ++k) {
            float4 s;
            s.x = pa[k].x + pb[k].x; s.y = pa[k].y + pb[k].y;
            s.z = pa[k].z + pb[k].z; s.w = pa[k].w + pb[k].w;
            s.x = s.x >= 0.f ? s.x : 0.2f * s.x;
            s.y = s.y >= 0.f ? s.y : 0.2f * s.y;
            s.z = s.z >= 0.f ? s.z : 0.2f * s.z;
            s.w = s.w >= 0.f ? s.w : 0.2f * s.w;
            float* dst = &xs[cur][k][srow * XS_STRIDE + 1 + sx4];
            dst[0] = s.x; dst[1] = s.y; dst[2] = s.z; dst[3] = s.w;
        }
        __syncthreads();

        if (cg4 + 4 < CMID) {
#pragma unroll
            for (int k = 0; k < 4; ++k) {
                pa[k] = gvalid ? *(const float4*)(gh0 + (size_t)(cg4 + 4 + k) * HW) : z4;
                pb[k] = gvalid ? *(const float4*)(gh1 + (size_t)(cg4 + 4 + k) * HW) : z4;
            }
        }

#pragma unroll
        for (int k = 0; k < 4; ++k) {
            float v[3][4];
            read_patch_lds(xs[cur][k], rl, px, v);
            int ci = cg4 + k;
#pragma unroll
            for (int kr = 0; kr < 3; ++kr)
#pragma unroll
                for (int kc = 0; kc < 3; ++kc) {
                    float2 wv = *(const float2*)(lw2 + (ci * 9 + kr * 3 + kc) * 2);
                    s0x = fmaf(v[kr][kc],     wv.x, s0x);
                    s0y = fmaf(v[kr][kc],     wv.y, s0y);
                    s1x = fmaf(v[kr][kc + 1], wv.x, s1x);
                    s1y = fmaf(v[kr][kc + 1], wv.y, s1y);
                }
        }
        cur ^= 1;
    }

    float ix0 = (float)px       + 0.1f * tanhf(s0x) * (0.5f * (float)(W - 1));
    float iy0 = (float)y        + 0.1f * tanhf(s0y) * (0.5f * (float)(H - 1));
    float ix1 = (float)(px + 1) + 0.1f * tanhf(s1x) * (0.5f * (float)(W - 1));
    float iy1 = (float)y        + 0.1f * tanhf(s1y) * (0.5f * (float)(H - 1));
    ix0 = fminf(fmaxf(ix0, 0.f), (float)(W - 1));
    iy0 = fminf(fmaxf(iy0, 0.f), (float)(H - 1));
    ix1 = fminf(fmaxf(ix1, 0.f), (float)(W - 1));
    iy1 = fminf(fmaxf(iy1, 0.f), (float)(H - 1));

    float4* op = (float4*)(off_buf + (size_t)b * HW + (size_t)y * W + px);
    *op = make_float4(ix0, iy0, ix1, iy1);
}

// ---------------------------------------------------------------------------
// Bilinear border sample via LDS row cache. FROZEN (r9).
// ---------------------------------------------------------------------------
#define SROWS 35
__global__ __launch_bounds__(256) void sample_kernel(const float* __restrict__ x,
                                                     const float2* __restrict__ off_buf,
                                                     float* __restrict__ out) {
    __shared__ float xs[SROWS * 256 + 2];    // +2: finite pad for row-34 +1 read

    int bid = blockIdx.x;                        // 0..127 tiles
    int sb = (bid & 7) * 16 + (bid >> 3);        // XCD-contiguous 16-tile bands
    int b  = sb >> 5;
    int ty = sb & 31;
    int cg = blockIdx.y;                         // 0..15 channel groups (4 ch)
    int tid = threadIdx.x;                       // column

    int ybase = ty << 3;
    int lo = ybase - 13;

    int a00[8], a10[8];
    float wx[8], wy[8];
    const float2* ob2 = off_buf + (size_t)b * HW + (size_t)ybase * W + tid;
#pragma unroll
    for (int r = 0; r < 8; ++r) {
        float2 o = ob2[r * W];
        float xf = floorf(o.x), yf = floorf(o.y);
        wx[r] = o.x - xf; wy[r] = o.y - yf;
        int x0 = (int)xf, yy0 = (int)yf;
        int yy1 = min(yy0 + 1, H - 1);
        a00[r] = ((yy0 - lo) << 8) + x0;
        a10[r] = ((yy1 - lo) << 8) + x0;
    }

    if (tid < 2) xs[SROWS * 256 + tid] = 0.f;    // init pad once (finite)

    const float* xb = x + ((size_t)b * C + cg * 4) * HW;
    float* outb = out + ((size_t)b * C + cg * 4) * HW + (size_t)ybase * W + tid;

#pragma unroll 1
    for (int c = 0; c < 4; ++c) {
        __syncthreads();
        const float* src = xb + (size_t)c * HW;
        for (int j = tid; j < SROWS * 64; j += 256) {
            int row = j >> 6, x4 = (j & 63) << 2;
            int grw = min(max(lo + row, 0), H - 1);
            *(float4*)&xs[(row << 8) + x4] = *(const float4*)(src + (size_t)grw * W + x4);
        }
        __syncthreads();
        float* oc = outb + (size_t)c * HW;
#pragma unroll
        for (int r = 0; r < 8; ++r) {
            float t0 = xs[a00[r]], t1 = xs[a00[r] + 1];   // ds_read2_b32
            float b0 = xs[a10[r]], b1 = xs[a10[r] + 1];   // ds_read2_b32
            float top = fmaf(wx[r], t1 - t0, t0);
            float bot = fmaf(wx[r], b1 - b0, b0);
            oc[r * W] = fmaf(wy[r], bot - top, top);
        }
    }
}

// ---------------------------------------------------------------------------
extern "C" void kernel_launch(void* const* d_in, const int* in_sizes, int n_in,
                              void* d_out, int out_size, void* d_ws, size_t ws_size,
                              hipStream_t stream) {
    const float* x  = (const float*)d_in[0];
    const float* w1 = (const float*)d_in[1];
    const float* b1 = (const float*)d_in[2];
    const float* w2 = (const float*)d_in[3];
    const float* b2 = (const float*)d_in[4];
    float* out = (float*)d_out;

    float* ws  = (float*)d_ws;
    float* wt  = ws;                                          // 16384 floats
    float* sim = ws + 16384;                                  // B*9*HW
    float* hp0 = sim + (size_t)B * 9 * HW;                    // B*16*HW
    float2* off_buf = (float2*)(hp0 + (size_t)B * CMID * HW); // B*HW float2
    float* hp1 = (float*)(off_buf + (size_t)B * HW);          // B*16*HW

    sim_kernel<<<512, 256, 0, stream>>>(x, sim, w1, wt);      // also fills wt
    conv1_kernel<<<1024, 256, 0, stream>>>(x, sim, wt, b1, hp0, hp1);
    offset_kernel<<<512, 256, 0, stream>>>(hp0, hp1, w2, b2, off_buf);
    sample_kernel<<<dim3(128, 16), 256, 0, stream>>>(x, off_buf, out);
}

// Round 12
// 237.037 us; speedup vs baseline: 1.0490x; 1.0490x over previous
//
#include <hip/hip_runtime.h>
#include <math.h>

#define B 4
#define C 64
#define H 256
#define W 256
#define CMID 16
#define CIN 73        // 64 + 9
#define HW (H*W)
#define NW (CIN*9*CMID)   // 10512 conv1 weights
#define XS_STRIDE 260     // offset kernel LDS row stride
#define PLN 258           // conv1 transposed row stride: 256 data + 2 halo slots
#define SE  258           // sim parity-split row stride

// ---------------------------------------------------------------------------
// Local cosine similarity. r8 structure + folded w1 transpose + CSQ-TABLE
// rewrite: nsq_p[d] == csq_{p+d}, so the 16 nsq-FMAs/thread/ch are replaced
// by 4 column-csq FMAs (from the register-held staged rows) and a 4x258 LDS
// table read in the epilogue. Per-ch VALU 34 -> 20 FMAs, VGPR -16.
// Out-of-image neighbors: csq=0 -> denominator cn*(0+eps), numerator 0 ==
// reference. Dots/staging/layout byte-identical to the verified r8 kernel.
// ---------------------------------------------------------------------------
__global__ __launch_bounds__(256) void sim_kernel(const float* __restrict__ x,
                                                  float* __restrict__ sim,
                                                  const float* __restrict__ w1,
                                                  float* __restrict__ wt) {
    __shared__ float xs[2][4][4 * SE];   // 33024 B
    __shared__ float csql[4][SE];        // rows y0-1..y0+2, col slot 1+c, 0/257 = 0

    int bid = blockIdx.x;
    int tid = threadIdx.x;

    {   // folded transpose: wt[(ci*9+k)*CMID+co] = w1[(co*CIN+ci)*9+k]
        int gidx = bid * 256 + tid;
        if (gidx < NW) {
            int co = gidx & (CMID - 1);
            int rest = gidx >> 4;
            int ci = rest / 9;
            int k = rest - ci * 9;
            wt[gidx] = w1[(co * CIN + ci) * 9 + k];
        }
    }

    int sb = (bid & 7) * 64 + (bid >> 3);    // XCD-contiguous bands (512 = 8*64)
    int b  = sb >> 7;
    int y0 = (sb & 127) << 1;
    int rl = tid >> 7;             // output row 0/1
    int k  = tid & 127;            // pixel-pair index
    int px = k << 1;
    int y  = y0 + rl;

    int scol = (tid & 1) ? 130 + (tid >> 1) : (tid >> 1);   // parity-split dst

    bool rv[4];
    size_t off[4];
#pragma unroll
    for (int j = 0; j < 4; ++j) {
        int grow = y0 - 1 + j;
        rv[j] = (grow >= 0) && (grow < H);
        off[j] = (size_t)grow * W + tid;
    }

    if (tid < 64) {   // zero slots 128/129: 2 bufs x 4 ch x 4 rows x 2
        int e = tid & 1;
        int r = (tid >> 1) & 3;
        int q = tid >> 3;          // buf*4 + ch
        (&xs[0][0][0])[q * (4 * SE) + r * SE + 128 + e] = 0.f;
    }
    if (tid < 8) csql[tid >> 1][(tid & 1) ? 257 : 0] = 0.f;   // col -1 / 256 pads

    float dot0[9], dot1[9];
#pragma unroll
    for (int i = 0; i < 9; ++i) { dot0[i] = dot1[i] = 0.f; }
    float csq4[4] = {0.f, 0.f, 0.f, 0.f};   // ||x[:, y0-1+j, tid]||^2

    const float* xb = x + (size_t)b * C * HW;
    float p[16];
#pragma unroll
    for (int kk = 0; kk < 4; ++kk)
#pragma unroll
        for (int j = 0; j < 4; ++j)
            p[kk * 4 + j] = rv[j] ? xb[(size_t)kk * HW + off[j]] : 0.f;

    int cur = 0;
#pragma unroll 1
    for (int cc = 0; cc < C; cc += 4) {
#pragma unroll
        for (int kk = 0; kk < 4; ++kk)
#pragma unroll
            for (int j = 0; j < 4; ++j)
                xs[cur][kk][j * SE + scol] = p[kk * 4 + j];

        // column csq from register-held staged values (4 FMA/ch equivalent)
#pragma unroll
        for (int kk = 0; kk < 4; ++kk)
#pragma unroll
            for (int j = 0; j < 4; ++j)
                csq4[j] = fmaf(p[kk * 4 + j], p[kk * 4 + j], csq4[j]);

        __syncthreads();

        if (cc + 4 < C) {
#pragma unroll
            for (int kk = 0; kk < 4; ++kk)
#pragma unroll
                for (int j = 0; j < 4; ++j)
                    p[kk * 4 + j] = rv[j] ? xb[(size_t)(cc + 4 + kk) * HW + off[j]] : 0.f;
        }

#pragma unroll
        for (int kk = 0; kk < 4; ++kk) {
            const float* base = &xs[cur][kk][rl * SE];
            float v[3][4];
#pragma unroll
            for (int r = 0; r < 3; ++r) {
                const float* rp = base + r * SE;
                v[r][0] = rp[129 + k];   // col px-1
                v[r][1] = rp[k];         // col px
                v[r][2] = rp[130 + k];   // col px+1
                v[r][3] = rp[k + 1];     // col px+2
            }
            float cv0 = v[1][1], cv1 = v[1][2];
#pragma unroll
            for (int kr = 0; kr < 3; ++kr)
#pragma unroll
                for (int kc = 0; kc < 3; ++kc) {
                    int kk9 = kr * 3 + kc;
                    if (kk9 == 4) continue;
                    dot0[kk9] = fmaf(cv0, v[kr][kc], dot0[kk9]);
                    dot1[kk9] = fmaf(cv1, v[kr][kc + 1], dot1[kk9]);
                }
        }
        cur ^= 1;
    }

    // epilogue: publish csq table, then normalize with neighbor csq
    __syncthreads();
#pragma unroll
    for (int j = 0; j < 4; ++j) csql[j][1 + tid] = csq4[j];
    __syncthreads();

    float csqo0 = csql[1 + rl][1 + px];
    float csqo1 = csql[1 + rl][2 + px];
    float cn0 = sqrtf(csqo0) + 1e-8f;
    float cn1 = sqrtf(csqo1) + 1e-8f;
    dot0[4] = csqo0;
    dot1[4] = csqo1;

    float* so = sim + (size_t)b * 9 * HW + (size_t)y * W + px;
#pragma unroll
    for (int kk9 = 0; kk9 < 9; ++kk9) {
        int dr = kk9 / 3, dc = kk9 - 3 * dr;
        float n0 = csql[rl + dr][px + dc];       // neighbor (y+dr-1, px+dc-1)
        float n1 = csql[rl + dr][px + 1 + dc];
        float s0 = dot0[kk9] / (cn0 * (sqrtf(n0) + 1e-8f));
        float s1 = dot1[kk9] / (cn1 * (sqrtf(n1) + 1e-8f));
        *(float2*)(so + (size_t)kk9 * HW) = make_float2(s0, s1);
    }
}

// ---------------------------------------------------------------------------
// Conv1 (73->16) + leaky. FROZEN at r10 (84.2 us): co-split waves, transposed
// conflict-free LDS, forced-VMEM dbuf weights, 4 ch/barrier, fused leaky.
// ---------------------------------------------------------------------------
__device__ __forceinline__ void conv1_co4(const float* __restrict__ pl, int l,
                                          int aL, int aR,
                                          const float4 wv[9], float4 acc[2][4]) {
    float v[4][6];
#pragma unroll
    for (int r = 0; r < 4; ++r) {
        const float* rp = pl + r * PLN;
        v[r][1] = rp[l];
        v[r][2] = rp[64 + l];
        v[r][3] = rp[128 + l];
        v[r][4] = rp[192 + l];
        v[r][0] = rp[aL];     // col 4l-1  (lane 0 -> slot 256 = 0)
        v[r][5] = rp[aR];     // col 4l+4  (lane 63 -> slot 257 = 0)
    }
#pragma unroll
    for (int kr = 0; kr < 3; ++kr)
#pragma unroll
        for (int kc = 0; kc < 3; ++kc) {
            float4 w = wv[kr * 3 + kc];
#pragma unroll
            for (int rr = 0; rr < 2; ++rr)
#pragma unroll
                for (int cc = 0; cc < 4; ++cc) {
                    float a = v[rr + kr][cc + kc];
                    acc[rr][cc].x = fmaf(a, w.x, acc[rr][cc].x);
                    acc[rr][cc].y = fmaf(a, w.y, acc[rr][cc].y);
                    acc[rr][cc].z = fmaf(a, w.z, acc[rr][cc].z);
                    acc[rr][cc].w = fmaf(a, w.w, acc[rr][cc].w);
                }
        }
}

__global__ __launch_bounds__(256) void conv1_kernel(const float* __restrict__ x,
                                                    const float* __restrict__ sim,
                                                    const float* __restrict__ wt,
                                                    const float* __restrict__ b1,
                                                    float* __restrict__ h) {
    __shared__ float xs[2][4][4 * PLN];   // 2 buf x 4 ch x 4 rows x 258 = 33024 B

    int tid = threadIdx.x;
    int l = tid & 63;
    int wid = tid >> 6;
    int bid = blockIdx.x;
    int sb = (bid & 7) * 64 + (bid >> 3);     // XCD-contiguous bands (512 = 8*64)
    int b  = sb >> 7;
    int y0 = (sb & 127) << 1;

    // Opaque VGPR zero: keeps wave-uniform weight loads on the VMEM path
    // (vmcnt), not the scalar path (lgkmcnt drain poison — r0/r1 lesson).
    int vz;
    asm volatile("v_mov_b32 %0, 0" : "=v"(vz));
    const float4* wq = (const float4*)wt + vz;

    const float* gx = x + (size_t)b * C * HW;
    const float* gs = sim + (size_t)b * 9 * HW;

    int grow = y0 - 1 + wid;
    bool rvw = (grow >= 0) && (grow < H);
    size_t goff = (size_t)grow * W + 4 * l;

    int aL = (l == 0)  ? 256 : 191 + l;
    int aR = (l == 63) ? 257 : l + 1;

    if (tid < 64) {   // zero halo slots: 2 bufs x 4 ch x 4 rows x {256,257}
        int e = tid & 1;
        int r = (tid >> 1) & 3;
        int q = tid >> 3;          // buf*4 + ch
        xs[q >> 2][q & 3][r * PLN + 256 + e] = 0.f;
    }

    float4 bias = ((const float4*)b1)[wid];
    float4 acc[2][4];
#pragma unroll
    for (int rr = 0; rr < 2; ++rr)
#pragma unroll
        for (int cc = 0; cc < 4; ++cc) acc[rr][cc] = bias;

    float4 wA[9], wB[9];
#pragma unroll
    for (int k = 0; k < 9; ++k) wA[k] = wq[k * 4 + wid];   // weights ch 0

    const float4 z4 = make_float4(0.f, 0.f, 0.f, 0.f);
    float4 p0 = z4, p1 = z4, p2 = z4, p3 = z4;
    if (rvw) {
        p0 = *(const float4*)(gx + goff);
        p1 = *(const float4*)(gx + HW + goff);
        p2 = *(const float4*)(gx + 2 * (size_t)HW + goff);
        p3 = *(const float4*)(gx + 3 * (size_t)HW + goff);
    }

    int cur = 0;
#pragma unroll 1
    for (int cc4 = 0; cc4 < 72; cc4 += 4) {
        {   // transposed staging: 4x b32 stride-1 per channel, 4 channels
            float* d0 = &xs[cur][0][wid * PLN];
            d0[l] = p0.x; d0[64 + l] = p0.y; d0[128 + l] = p0.z; d0[192 + l] = p0.w;
            float* d1 = &xs[cur][1][wid * PLN];
            d1[l] = p1.x; d1[64 + l] = p1.y; d1[128 + l] = p1.z; d1[192 + l] = p1.w;
            float* d2 = &xs[cur][2][wid * PLN];
            d2[l] = p2.x; d2[64 + l] = p2.y; d2[128 + l] = p2.z; d2[192 + l] = p2.w;
            float* d3 = &xs[cur][3][wid * PLN];
            d3[l] = p3.x; d3[64 + l] = p3.y; d3[128 + l] = p3.z; d3[192 + l] = p3.w;
        }
        __syncthreads();

        // prefetch activations cc4+4..cc4+7 (uniform guards; at cc4=68 only
        // ch 72 is valid -> lands in p0 for the tail)
        {
            int c0 = cc4 + 4;
            p0 = z4;
            if (rvw && c0 < CIN)
                p0 = (c0 < C) ? *(const float4*)(gx + (size_t)c0 * HW + goff)
                              : *(const float4*)(gs + (size_t)(c0 - C) * HW + goff);
            int c1 = cc4 + 5;
            p1 = z4;
            if (rvw && c1 < CIN)
                p1 = (c1 < C) ? *(const float4*)(gx + (size_t)c1 * HW + goff)
                              : *(const float4*)(gs + (size_t)(c1 - C) * HW + goff);
            int c2 = cc4 + 6;
            p2 = z4;
            if (rvw && c2 < CIN)
                p2 = (c2 < C) ? *(const float4*)(gx + (size_t)c2 * HW + goff)
                              : *(const float4*)(gs + (size_t)(c2 - C) * HW + goff);
            int c3 = cc4 + 7;
            p3 = z4;
            if (rvw && c3 < CIN)
                p3 = (c3 < C) ? *(const float4*)(gx + (size_t)c3 * HW + goff)
                              : *(const float4*)(gs + (size_t)(c3 - C) * HW + goff);
        }

        // weight dbuf alternation across the 4 staged channels
#pragma unroll
        for (int k = 0; k < 9; ++k) wB[k] = wq[((cc4 + 1) * 9 + k) * 4 + wid];
        conv1_co4(&xs[cur][0][0], l, aL, aR, wA, acc);      // ch cc4

#pragma unroll
        for (int k = 0; k < 9; ++k) wA[k] = wq[((cc4 + 2) * 9 + k) * 4 + wid];
        conv1_co4(&xs[cur][1][0], l, aL, aR, wB, acc);      // ch cc4+1

#pragma unroll
        for (int k = 0; k < 9; ++k) wB[k] = wq[((cc4 + 3) * 9 + k) * 4 + wid];
        conv1_co4(&xs[cur][2][0], l, aL, aR, wA, acc);      // ch cc4+2

#pragma unroll
        for (int k = 0; k < 9; ++k) wA[k] = wq[((cc4 + 4) * 9 + k) * 4 + wid];
        conv1_co4(&xs[cur][3][0], l, aL, aR, wB, acc);      // ch cc4+3

        cur ^= 1;
    }

    // tail channel ci = 72 (activations in p0, weights in wA)
    {
        float* d0 = &xs[cur][0][wid * PLN];
        d0[l] = p0.x; d0[64 + l] = p0.y; d0[128 + l] = p0.z; d0[192 + l] = p0.w;
    }
    __syncthreads();
    conv1_co4(&xs[cur][0][0], l, aL, aR, wA, acc);

    // epilogue: leaky, transpose acc (col-vector-of-co -> co-planes), float4 stores
    float* ho = h + ((size_t)b * CMID + 4 * wid) * HW + (size_t)y0 * W + 4 * l;
#pragma unroll
    for (int rr = 0; rr < 2; ++rr)
#pragma unroll
        for (int j = 0; j < 4; ++j) {
            float4 o;
            o.x = ((const float*)&acc[rr][0])[j];
            o.y = ((const float*)&acc[rr][1])[j];
            o.z = ((const float*)&acc[rr][2])[j];
            o.w = ((const float*)&acc[rr][3])[j];
            o.x = o.x >= 0.f ? o.x : 0.2f * o.x;
            o.y = o.y >= 0.f ? o.y : 0.2f * o.y;
            o.z = o.z >= 0.f ? o.z : 0.2f * o.z;
            o.w = o.w >= 0.f ? o.w : 0.2f * o.w;
            *(float4*)(ho + (size_t)j * HW + (size_t)rr * W) = o;
        }
}

// ---------------------------------------------------------------------------
// Strip helpers for offset kernel (2-px/thread structure, stride 260).
// ---------------------------------------------------------------------------
__device__ __forceinline__ void read_patch_lds(const float* __restrict__ xsbuf,
                                               int rl, int px, float v[3][4]) {
    const float* pb = xsbuf + rl * XS_STRIDE + px;
#pragma unroll
    for (int r = 0; r < 3; ++r) {
        float2 p0 = *(const float2*)(pb + r * XS_STRIDE);
        float2 p1 = *(const float2*)(pb + r * XS_STRIDE + 2);
        v[r][0] = p0.x; v[r][1] = p0.y; v[r][2] = p1.x; v[r][3] = p1.y;
    }
}

// ---------------------------------------------------------------------------
// Conv2 (16->2) + tanh -> clamped sample coords. FROZEN (r9: 4 ch/barrier).
// ---------------------------------------------------------------------------
__global__ __launch_bounds__(256) void offset_kernel(const float* __restrict__ h,
                                                     const float* __restrict__ w2,
                                                     const float* __restrict__ b2,
                                                     float2* __restrict__ off_buf) {
    __shared__ float lw2[CMID * 9 * 2];
    __shared__ float xs[2][4][4 * XS_STRIDE];   // 33280 B

    int tid = threadIdx.x;
    for (int i = tid; i < CMID * 9 * 2; i += 256) {
        int co = i & 1;
        int rest = i >> 1;
        int ci = rest / 9;
        int kk = rest - ci * 9;
        lw2[i] = w2[(co * CMID + ci) * 9 + kk];
    }

    int bid = blockIdx.x;
    int sb = (bid & 7) * 64 + (bid >> 3);    // XCD-contiguous bands (512 = 8*64)
    int b  = sb >> 7;
    int y0 = (sb & 127) << 1;
    int srow = tid >> 6;
    int sx4  = (tid & 63) << 2;
    int rl = tid >> 7;
    int px = (tid & 127) << 1;
    int y  = y0 + rl;

    int grow = y0 - 1 + srow;
    bool gvalid = (grow >= 0) && (grow < H);
    const float* gh = h + (size_t)b * CMID * HW + (size_t)grow * W + sx4;

    if (tid < 64) {   // zero halo cols: 2 bufs x 4 ch x 4 rows x {0,257}
        int bu = tid >> 5, ch = (tid >> 3) & 3, r = (tid >> 1) & 3;
        int e = (tid & 1) ? 257 : 0;
        xs[bu][ch][r * XS_STRIDE + e] = 0.f;
    }

    float s0x = b2[0], s0y = b2[1], s1x = b2[0], s1y = b2[1];

    const float4 z4 = make_float4(0.f, 0.f, 0.f, 0.f);
    float4 pr[4];
#pragma unroll
    for (int k = 0; k < 4; ++k)
        pr[k] = gvalid ? *(const float4*)(gh + (size_t)k * HW) : z4;

    int cur = 0;
#pragma unroll 1
    for (int cg4 = 0; cg4 < CMID; cg4 += 4) {
#pragma unroll
        for (int k = 0; k < 4; ++k) {
            float* dst = &xs[cur][k][srow * XS_STRIDE + 1 + sx4];
            dst[0] = pr[k].x; dst[1] = pr[k].y; dst[2] = pr[k].z; dst[3] = pr[k].w;
        }
        __syncthreads();

        if (cg4 + 4 < CMID) {
#pragma unroll
            for (int k = 0; k < 4; ++k)
                pr[k] = gvalid ? *(const float4*)(gh + (size_t)(cg4 + 4 + k) * HW) : z4;
        }

#pragma unroll
        for (int k = 0; k < 4; ++k) {
            float v[3][4];
            read_patch_lds(xs[cur][k], rl, px, v);
            int ci = cg4 + k;
#pragma unroll
            for (int kr = 0; kr < 3; ++kr)
#pragma unroll
                for (int kc = 0; kc < 3; ++kc) {
                    float2 wv = *(const float2*)(lw2 + (ci * 9 + kr * 3 + kc) * 2);
                    s0x = fmaf(v[kr][kc],     wv.x, s0x);
                    s0y = fmaf(v[kr][kc],     wv.y, s0y);
                    s1x = fmaf(v[kr][kc + 1], wv.x, s1x);
                    s1y = fmaf(v[kr][kc + 1], wv.y, s1y);
                }
        }
        cur ^= 1;
    }

    float ix0 = (float)px       + 0.1f * tanhf(s0x) * (0.5f * (float)(W - 1));
    float iy0 = (float)y        + 0.1f * tanhf(s0y) * (0.5f * (float)(H - 1));
    float ix1 = (float)(px + 1) + 0.1f * tanhf(s1x) * (0.5f * (float)(W - 1));
    float iy1 = (float)y        + 0.1f * tanhf(s1y) * (0.5f * (float)(H - 1));
    ix0 = fminf(fmaxf(ix0, 0.f), (float)(W - 1));
    iy0 = fminf(fmaxf(iy0, 0.f), (float)(H - 1));
    ix1 = fminf(fmaxf(ix1, 0.f), (float)(W - 1));
    iy1 = fminf(fmaxf(iy1, 0.f), (float)(H - 1));

    float4* op = (float4*)(off_buf + (size_t)b * HW + (size_t)y * W + px);
    *op = make_float4(ix0, iy0, ix1, iy1);
}

// ---------------------------------------------------------------------------
// Bilinear border sample via LDS row cache. FROZEN (r9).
// ---------------------------------------------------------------------------
#define SROWS 35
__global__ __launch_bounds__(256) void sample_kernel(const float* __restrict__ x,
                                                     const float2* __restrict__ off_buf,
                                                     float* __restrict__ out) {
    __shared__ float xs[SROWS * 256 + 2];    // +2: finite pad for row-34 +1 read

    int bid = blockIdx.x;                        // 0..127 tiles
    int sb = (bid & 7) * 16 + (bid >> 3);        // XCD-contiguous 16-tile bands
    int b  = sb >> 5;
    int ty = sb & 31;
    int cg = blockIdx.y;                         // 0..15 channel groups (4 ch)
    int tid = threadIdx.x;                       // column

    int ybase = ty << 3;
    int lo = ybase - 13;

    int a00[8], a10[8];
    float wx[8], wy[8];
    const float2* ob2 = off_buf + (size_t)b * HW + (size_t)ybase * W + tid;
#pragma unroll
    for (int r = 0; r < 8; ++r) {
        float2 o = ob2[r * W];
        float xf = floorf(o.x), yf = floorf(o.y);
        wx[r] = o.x - xf; wy[r] = o.y - yf;
        int x0 = (int)xf, yy0 = (int)yf;
        int yy1 = min(yy0 + 1, H - 1);
        a00[r] = ((yy0 - lo) << 8) + x0;
        a10[r] = ((yy1 - lo) << 8) + x0;
    }

    if (tid < 2) xs[SROWS * 256 + tid] = 0.f;    // init pad once (finite)

    const float* xb = x + ((size_t)b * C + cg * 4) * HW;
    float* outb = out + ((size_t)b * C + cg * 4) * HW + (size_t)ybase * W + tid;

#pragma unroll 1
    for (int c = 0; c < 4; ++c) {
        __syncthreads();
        const float* src = xb + (size_t)c * HW;
        for (int j = tid; j < SROWS * 64; j += 256) {
            int row = j >> 6, x4 = (j & 63) << 2;
            int grw = min(max(lo + row, 0), H - 1);
            *(float4*)&xs[(row << 8) + x4] = *(const float4*)(src + (size_t)grw * W + x4);
        }
        __syncthreads();
        float* oc = outb + (size_t)c * HW;
#pragma unroll
        for (int r = 0; r < 8; ++r) {
            float t0 = xs[a00[r]], t1 = xs[a00[r] + 1];   // ds_read2_b32
            float b0 = xs[a10[r]], b1 = xs[a10[r] + 1];   // ds_read2_b32
            float top = fmaf(wx[r], t1 - t0, t0);
            float bot = fmaf(wx[r], b1 - b0, b0);
            oc[r * W] = fmaf(wy[r], bot - top, top);
        }
    }
}

// ---------------------------------------------------------------------------
extern "C" void kernel_launch(void* const* d_in, const int* in_sizes, int n_in,
                              void* d_out, int out_size, void* d_ws, size_t ws_size,
                              hipStream_t stream) {
    const float* x  = (const float*)d_in[0];
    const float* w1 = (const float*)d_in[1];
    const float* b1 = (const float*)d_in[2];
    const float* w2 = (const float*)d_in[3];
    const float* b2 = (const float*)d_in[4];
    float* out = (float*)d_out;

    float* ws  = (float*)d_ws;
    float* wt  = ws;                                         // 16384 floats
    float* sim = ws + 16384;                                 // B*9*HW
    float* h   = sim + (size_t)B * 9 * HW;                   // B*16*HW
    float2* off_buf = (float2*)(h + (size_t)B * CMID * HW);  // B*HW float2

    sim_kernel<<<512, 256, 0, stream>>>(x, sim, w1, wt);     // also fills wt
    conv1_kernel<<<512, 256, 0, stream>>>(x, sim, wt, b1, h);
    offset_kernel<<<512, 256, 0, stream>>>(h, w2, b2, off_buf);
    sample_kernel<<<dim3(128, 16), 256, 0, stream>>>(x, off_buf, out);
}